// Round 1
// baseline (360.391 us; speedup 1.0000x reference)
//
#include <hip/hip_runtime.h>
#include <hip/hip_bf16.h>

#define SEQ 4096
#define DIM 768
#define NH  12
#define HDK 64

typedef __attribute__((ext_vector_type(8))) short bf16x8;
typedef __attribute__((ext_vector_type(4))) float f32x4;

static __device__ __forceinline__ unsigned short f2b(float f) {
    // round-to-nearest-even bf16
    unsigned int u = __float_as_uint(f);
    unsigned int lsb = (u >> 16) & 1u;
    u += 0x7fffu + lsb;
    return (unsigned short)(u >> 16);
}

static __device__ __forceinline__ void storebf4(short* p, float4 v) {
    unsigned int a = (unsigned int)f2b(v.x) | ((unsigned int)f2b(v.y) << 16);
    unsigned int b = (unsigned int)f2b(v.z) | ((unsigned int)f2b(v.w) << 16);
    *(uint2*)p = make_uint2(a, b);
}

// 8 bf16 from LDS via two 8B reads (rows are 8B-aligned, not 16B)
static __device__ __forceinline__ bf16x8 ldfrag(const short* p) {
    union { bf16x8 v; uint2 u[2]; } r;
    r.u[0] = *(const uint2*)(p);
    r.u[1] = *(const uint2*)(p + 4);
    return r.v;
}

// 8 bf16 from global, 16B aligned
static __device__ __forceinline__ bf16x8 ldfrag_g(const unsigned short* p) {
    union { bf16x8 v; uint4 u; } r;
    r.u = *(const uint4*)p;
    return r.v;
}

// ---------------- Projection GEMM: Y = x @ W^T + b, output bf16 ----------------
// x: [SEQ, DIM] f32, W: [DIM, DIM] f32 (row = out feature -> already B^T layout)
// grid: (DIM/128, SEQ/128, 3), block 256
__global__ __launch_bounds__(256) void proj_kernel(
    const float* __restrict__ x,
    const float* __restrict__ Wq, const float* __restrict__ bq,
    const float* __restrict__ Wk, const float* __restrict__ bk,
    const float* __restrict__ Wv, const float* __restrict__ bv,
    unsigned short* __restrict__ Qb, unsigned short* __restrict__ Kb,
    unsigned short* __restrict__ Vb)
{
    const int z = blockIdx.z;
    const float* W    = (z == 0) ? Wq : (z == 1) ? Wk : Wv;
    const float* bias = (z == 0) ? bq : (z == 1) ? bk : bv;
    unsigned short* out = (z == 0) ? Qb : (z == 1) ? Kb : Vb;

    const int n0 = blockIdx.x * 128;
    const int m0 = blockIdx.y * 128;
    const int tid = threadIdx.x;
    const int w  = tid >> 6, ln = tid & 63;
    const int wr = w >> 1,  wc = w & 1;

    __shared__ short A_lds[128][40];  // 32 + 8 pad (80B rows: spreads banks)
    __shared__ short B_lds[128][40];

    const f32x4 fzero = {0.f, 0.f, 0.f, 0.f};
    f32x4 acc[4][4];
    #pragma unroll
    for (int m = 0; m < 4; m++)
        #pragma unroll
        for (int n = 0; n < 4; n++) acc[m][n] = fzero;

    const int rsel = ln & 15;
    const int kb8  = (ln >> 4) * 8;

    for (int k0 = 0; k0 < DIM; k0 += 32) {
        __syncthreads();
        #pragma unroll
        for (int i = 0; i < 4; i++) {
            int idx = tid + i * 256;
            int row = idx >> 3, ch = idx & 7;           // 8 chunks of 4 floats per 32-wide row
            float4 a = *(const float4*)(x + (size_t)(m0 + row) * DIM + k0 + ch * 4);
            float4 b = *(const float4*)(W + (size_t)(n0 + row) * DIM + k0 + ch * 4);
            storebf4(&A_lds[row][ch * 4], a);
            storebf4(&B_lds[row][ch * 4], b);
        }
        __syncthreads();

        bf16x8 af[4], bf[4];
        #pragma unroll
        for (int m = 0; m < 4; m++) af[m] = ldfrag(&A_lds[wr * 64 + m * 16 + rsel][kb8]);
        #pragma unroll
        for (int n = 0; n < 4; n++) bf[n] = ldfrag(&B_lds[wc * 64 + n * 16 + rsel][kb8]);
        #pragma unroll
        for (int m = 0; m < 4; m++)
            #pragma unroll
            for (int n = 0; n < 4; n++)
                acc[m][n] = __builtin_amdgcn_mfma_f32_16x16x32_bf16(af[m], bf[n], acc[m][n], 0, 0, 0);
    }

    // epilogue: + bias, cast bf16, store
    const int r0 = (ln >> 4) * 4;
    #pragma unroll
    for (int n = 0; n < 4; n++) {
        int col = n0 + wc * 64 + n * 16 + rsel;
        float bcol = bias[col];
        #pragma unroll
        for (int m = 0; m < 4; m++) {
            #pragma unroll
            for (int r = 0; r < 4; r++) {
                int row = m0 + wr * 64 + m * 16 + r0 + r;
                out[(size_t)row * DIM + col] = f2b(acc[m][n][r] + bcol);
            }
        }
    }
}

// ---------------- Flash attention ----------------
// grid: (SEQ/64, NH), block 256 (4 waves; each wave owns 16 q rows)
__global__ __launch_bounds__(256) void attn_kernel(
    const unsigned short* __restrict__ Qb,
    const unsigned short* __restrict__ Kb,
    const unsigned short* __restrict__ Vb,
    float* __restrict__ out)
{
    const int h  = blockIdx.y;
    const int q0 = blockIdx.x * 64;
    const int tid = threadIdx.x;
    const int w  = tid >> 6, ln = tid & 63;
    const int qw = q0 + w * 16;

    __shared__ short K_lds[64][72];      // [key][dim], 144B rows (8B aligned)
    __shared__ short Vt_lds[64][72];     // [dim][key]
    __shared__ short P_lds[4][16][72];   // per wave: [qrow][key]

    const int rsel = ln & 15;
    const int kb8  = (ln >> 4) * 8;
    const float scale = 0.125f;          // 1/sqrt(64)

    // Q fragments (A-operand: row = lane&15, 8 consecutive k)
    bf16x8 qf[2];
    {
        const unsigned short* qp = Qb + (size_t)(qw + rsel) * DIM + h * HDK;
        qf[0] = ldfrag_g(qp + kb8);
        qf[1] = ldfrag_g(qp + 32 + kb8);
    }

    const f32x4 fzero = {0.f, 0.f, 0.f, 0.f};
    float m_run[4], l_run[4];
    f32x4 acc_o[4];
    #pragma unroll
    for (int r = 0; r < 4; r++) { m_run[r] = -1e30f; l_run[r] = 0.f; }
    #pragma unroll
    for (int n = 0; n < 4; n++) acc_o[n] = fzero;

    const int prow0 = (ln >> 4) * 4;

    for (int kt = 0; kt < SEQ / 64; kt++) {
        const int kbase = kt * 64;
        // stage K (as-is) and V (transposed)
        #pragma unroll
        for (int i = 0; i < 2; i++) {
            int idx = tid + i * 256;
            int row = idx >> 3, ch = idx & 7;   // 8 chunks of 8 bf16 per 64-wide row
            union { uint4 u; unsigned short s[8]; } kv, vv;
            kv.u = *(const uint4*)(Kb + (size_t)(kbase + row) * DIM + h * HDK + ch * 8);
            *(uint2*)&K_lds[row][ch * 8]     = make_uint2(kv.u.x, kv.u.y);
            *(uint2*)&K_lds[row][ch * 8 + 4] = make_uint2(kv.u.z, kv.u.w);
            vv.u = *(const uint4*)(Vb + (size_t)(kbase + row) * DIM + h * HDK + ch * 8);
            #pragma unroll
            for (int j = 0; j < 8; j++) Vt_lds[ch * 8 + j][row] = (short)vv.s[j];
        }
        __syncthreads();

        // S = Q K^T (scaled)
        f32x4 accs[4];
        #pragma unroll
        for (int n = 0; n < 4; n++) accs[n] = fzero;
        #pragma unroll
        for (int kk = 0; kk < 2; kk++) {
            #pragma unroll
            for (int n = 0; n < 4; n++) {
                bf16x8 kf = ldfrag(&K_lds[n * 16 + rsel][kk * 32 + kb8]);
                accs[n] = __builtin_amdgcn_mfma_f32_16x16x32_bf16(qf[kk], kf, accs[n], 0, 0, 0);
            }
        }

        // online softmax: rows spread across (lane&15) x n-frags
        float p[4][4];
        #pragma unroll
        for (int n = 0; n < 4; n++)
            #pragma unroll
            for (int r = 0; r < 4; r++) p[n][r] = accs[n][r] * scale;

        #pragma unroll
        for (int r = 0; r < 4; r++) {
            float mt = fmaxf(fmaxf(p[0][r], p[1][r]), fmaxf(p[2][r], p[3][r]));
            #pragma unroll
            for (int mask = 1; mask < 16; mask <<= 1) mt = fmaxf(mt, __shfl_xor(mt, mask));
            float mnew  = fmaxf(m_run[r], mt);
            float alpha = __expf(m_run[r] - mnew);
            float rs = 0.f;
            #pragma unroll
            for (int n = 0; n < 4; n++) { p[n][r] = __expf(p[n][r] - mnew); rs += p[n][r]; }
            #pragma unroll
            for (int mask = 1; mask < 16; mask <<= 1) rs += __shfl_xor(rs, mask);
            l_run[r] = l_run[r] * alpha + rs;
            m_run[r] = mnew;
            #pragma unroll
            for (int n = 0; n < 4; n++) acc_o[n][r] *= alpha;
        }

        // P -> LDS (re-layout D-frag -> A-frag), bf16
        #pragma unroll
        for (int n = 0; n < 4; n++)
            #pragma unroll
            for (int r = 0; r < 4; r++)
                P_lds[w][prow0 + r][n * 16 + rsel] = (short)f2b(p[n][r]);

        // O += P V  (A = P [q][key], B = V^T [dim][key])
        #pragma unroll
        for (int kk = 0; kk < 2; kk++) {
            bf16x8 pf = ldfrag(&P_lds[w][rsel][kk * 32 + kb8]);
            #pragma unroll
            for (int n = 0; n < 4; n++) {
                bf16x8 vf = ldfrag(&Vt_lds[n * 16 + rsel][kk * 32 + kb8]);
                acc_o[n] = __builtin_amdgcn_mfma_f32_16x16x32_bf16(pf, vf, acc_o[n], 0, 0, 0);
            }
        }
        __syncthreads();
    }

    // epilogue: normalize, store fp32
    #pragma unroll
    for (int n = 0; n < 4; n++) {
        #pragma unroll
        for (int r = 0; r < 4; r++) {
            int row = qw + prow0 + r;
            int col = h * HDK + n * 16 + rsel;
            out[(size_t)row * DIM + col] = acc_o[n][r] / l_run[r];
        }
    }
}

extern "C" void kernel_launch(void* const* d_in, const int* in_sizes, int n_in,
                              void* d_out, int out_size, void* d_ws, size_t ws_size,
                              hipStream_t stream) {
    const float* x  = (const float*)d_in[0];
    const float* Wq = (const float*)d_in[1];
    const float* bq = (const float*)d_in[2];
    const float* Wk = (const float*)d_in[3];
    const float* bk = (const float*)d_in[4];
    const float* Wv = (const float*)d_in[5];
    const float* bv = (const float*)d_in[6];
    float* out = (float*)d_out;

    unsigned short* Qb = (unsigned short*)d_ws;
    unsigned short* Kb = Qb + (size_t)SEQ * DIM;
    unsigned short* Vb = Kb + (size_t)SEQ * DIM;

    dim3 g1(DIM / 128, SEQ / 128, 3);
    proj_kernel<<<g1, 256, 0, stream>>>(x, Wq, bq, Wk, bk, Wv, bv, Qb, Kb, Vb);

    dim3 g2(SEQ / 64, NH);
    attn_kernel<<<g2, 256, 0, stream>>>(Qb, Kb, Vb, out);
}

// Round 2
// 261.375 us; speedup vs baseline: 1.3788x; 1.3788x over previous
//
#include <hip/hip_runtime.h>
#include <hip/hip_bf16.h>

#define SEQ 4096
#define DIM 768
#define NH  12
#define HDK 64
#define NT  (SEQ / 64)

typedef __attribute__((ext_vector_type(8))) short bf16x8;
typedef __attribute__((ext_vector_type(4))) float f32x4;

static __device__ __forceinline__ unsigned short f2b(float f) {
    unsigned int u = __float_as_uint(f);
    unsigned int lsb = (u >> 16) & 1u;
    u += 0x7fffu + lsb;
    return (unsigned short)(u >> 16);
}

static __device__ __forceinline__ void storebf4(short* p, float4 v) {
    unsigned int a = (unsigned int)f2b(v.x) | ((unsigned int)f2b(v.y) << 16);
    unsigned int b = (unsigned int)f2b(v.z) | ((unsigned int)f2b(v.w) << 16);
    *(uint2*)p = make_uint2(a, b);
}

static __device__ __forceinline__ bf16x8 ldfrag(const short* p) {
    union { bf16x8 v; uint2 u[2]; } r;
    r.u[0] = *(const uint2*)(p);
    r.u[1] = *(const uint2*)(p + 4);
    return r.v;
}

static __device__ __forceinline__ bf16x8 ldfrag16(const short* p) {
    union { bf16x8 v; uint4 u; } r;
    r.u = *(const uint4*)p;
    return r.v;
}

static __device__ __forceinline__ bf16x8 ldfrag_g(const unsigned short* p) {
    union { bf16x8 v; uint4 u; } r;
    r.u = *(const uint4*)p;
    return r.v;
}

static __device__ __forceinline__ unsigned int cvtpk(float lo, float hi) {
    unsigned int r;
    asm("v_cvt_pk_bf16_f32 %0, %1, %2" : "=v"(r) : "v"(lo), "v"(hi));
    return r;
}

static __device__ __forceinline__ void gload16(const void* g, void* l) {
    __builtin_amdgcn_global_load_lds(
        (const __attribute__((address_space(1))) unsigned int*)g,
        (__attribute__((address_space(3))) unsigned int*)l, 16, 0, 0);
}

// ---------------- Projection GEMM ----------------
// z==0: Q = x@Wq^T+bq  -> Qb [SEQ][DIM] bf16
// z==1: K              -> Kb [SEQ][DIM] bf16
// z==2: V^T            -> Vt [DIM][SEQ] bf16 (transposed store via swapped MFMA operands)
__global__ __launch_bounds__(256) void proj_kernel(
    const float* __restrict__ x,
    const float* __restrict__ Wq, const float* __restrict__ bq,
    const float* __restrict__ Wk, const float* __restrict__ bk,
    const float* __restrict__ Wv, const float* __restrict__ bv,
    unsigned short* __restrict__ Qb, unsigned short* __restrict__ Kb,
    unsigned short* __restrict__ Vt)
{
    const int z = blockIdx.z;
    const float* W    = (z == 0) ? Wq : (z == 1) ? Wk : Wv;
    const float* bias = (z == 0) ? bq : (z == 1) ? bk : bv;
    const bool tr = (z == 2);

    const int n0 = blockIdx.x * 128;
    const int m0 = blockIdx.y * 128;
    const int tid = threadIdx.x;
    const int w  = tid >> 6, ln = tid & 63;
    const int wr = w >> 1,  wc = w & 1;

    __shared__ short A_lds[128][40];
    __shared__ short B_lds[128][40];

    const f32x4 fzero = {0.f, 0.f, 0.f, 0.f};
    f32x4 acc[4][4];
    #pragma unroll
    for (int m = 0; m < 4; m++)
        #pragma unroll
        for (int n = 0; n < 4; n++) acc[m][n] = fzero;

    const int rsel = ln & 15;
    const int kb8  = (ln >> 4) * 8;

    for (int k0 = 0; k0 < DIM; k0 += 32) {
        __syncthreads();
        #pragma unroll
        for (int i = 0; i < 4; i++) {
            int idx = tid + i * 256;
            int row = idx >> 3, ch = idx & 7;
            float4 a = *(const float4*)(x + (size_t)(m0 + row) * DIM + k0 + ch * 4);
            float4 b = *(const float4*)(W + (size_t)(n0 + row) * DIM + k0 + ch * 4);
            storebf4(&A_lds[row][ch * 4], a);
            storebf4(&B_lds[row][ch * 4], b);
        }
        __syncthreads();

        bf16x8 af[4], bf[4];
        #pragma unroll
        for (int m = 0; m < 4; m++) af[m] = ldfrag(&A_lds[wr * 64 + m * 16 + rsel][kb8]);
        #pragma unroll
        for (int n = 0; n < 4; n++) bf[n] = ldfrag(&B_lds[wc * 64 + n * 16 + rsel][kb8]);
        if (!tr) {
            #pragma unroll
            for (int m = 0; m < 4; m++)
                #pragma unroll
                for (int n = 0; n < 4; n++)
                    acc[m][n] = __builtin_amdgcn_mfma_f32_16x16x32_bf16(af[m], bf[n], acc[m][n], 0, 0, 0);
        } else {
            #pragma unroll
            for (int m = 0; m < 4; m++)
                #pragma unroll
                for (int n = 0; n < 4; n++)
                    acc[m][n] = __builtin_amdgcn_mfma_f32_16x16x32_bf16(bf[n], af[m], acc[m][n], 0, 0, 0);
        }
    }

    const int r0 = (ln >> 4) * 4;
    if (!tr) {
        unsigned short* out = (z == 0) ? Qb : Kb;
        #pragma unroll
        for (int n = 0; n < 4; n++) {
            int col = n0 + wc * 64 + n * 16 + rsel;
            float bcol = bias[col];
            #pragma unroll
            for (int m = 0; m < 4; m++) {
                #pragma unroll
                for (int r = 0; r < 4; r++) {
                    int row = m0 + wr * 64 + m * 16 + r0 + r;
                    out[(size_t)row * DIM + col] = f2b(acc[m][n][r] + bcol);
                }
            }
        }
    } else {
        // D rows = W features f, D cols = sequence s
        #pragma unroll
        for (int n = 0; n < 4; n++) {
            float bv_[4];
            #pragma unroll
            for (int r = 0; r < 4; r++) bv_[r] = bias[n0 + wc * 64 + n * 16 + r0 + r];
            #pragma unroll
            for (int m = 0; m < 4; m++) {
                int s = m0 + wr * 64 + m * 16 + rsel;
                #pragma unroll
                for (int r = 0; r < 4; r++) {
                    int f = n0 + wc * 64 + n * 16 + r0 + r;
                    Vt[(size_t)f * SEQ + s] = f2b(acc[m][n][r] + bv_[r]);
                }
            }
        }
    }
}

// ---------------- Flash attention ----------------
// grid: (SEQ/64, NH), block 256 (4 waves; each wave owns 16 q rows)
// Swapped QK^T (S^T in regs), in-register softmax, P via per-wave swizzled LDS,
// K/V staged by global_load_lds with pre-swizzled source, double-buffered.
__global__ __launch_bounds__(256) void attn_kernel(
    const unsigned short* __restrict__ Qb,
    const unsigned short* __restrict__ Kb,
    const unsigned short* __restrict__ Vt,   // [DIM][SEQ]
    float* __restrict__ out)
{
    const int h  = blockIdx.y;
    const int q0 = blockIdx.x * 64;
    const int tid = threadIdx.x;
    const int w  = tid >> 6, ln = tid & 63;
    const int qw = q0 + w * 16;
    const int lq = ln & 15;          // q column (S^T) / d column (O) / frag row sel
    const int g  = ln >> 4;          // 0..3
    const int l7 = ln & 7;
    const int ln3 = ln >> 3;         // 0..7
    const int slotp = l7 ^ ln3;      // pre-swizzled global 16B chunk

    __shared__ short K_lds[2][64][64];
    __shared__ short V_lds[2][64][64];
    __shared__ short P_lds[4][16][64];

    // Q fragments (B-operand: col=lq, k = d = kk*32 + g*8 + 0..7)
    bf16x8 qf[2];
    {
        const unsigned short* qp = Qb + (size_t)(qw + lq) * DIM + h * HDK + g * 8;
        qf[0] = ldfrag_g(qp);
        qf[1] = ldfrag_g(qp + 32);
    }

    // staging pointers (pre-swizzled source chunks)
    const char* kg = (const char*)Kb + (((size_t)(w * 16 + ln3)) * DIM + h * HDK) * 2 + slotp * 16;
    const char* vg = (const char*)Vt + (((size_t)(h * HDK + w * 16 + ln3)) * SEQ) * 2 + slotp * 16;
    const size_t kstep  = (size_t)64 * DIM * 2;  // K bytes per key-tile
    const size_t kstep8 = (size_t)8 * DIM * 2;   // 8 rows
    const size_t vstep8 = (size_t)8 * SEQ * 2;

    // hoisted per-lane LDS offsets (shorts) for swizzled b128 frag reads
    int swzA[2];
    #pragma unroll
    for (int kk = 0; kk < 2; kk++) swzA[kk] = ((kk * 64 + g * 16) ^ (l7 << 4)) >> 1;
    int pwoff[4];
    #pragma unroll
    for (int n = 0; n < 4; n++) pwoff[n] = lq * 128 + ((n * 32 + g * 8) ^ (l7 << 4));

    const f32x4 fzero = {0.f, 0.f, 0.f, 0.f};
    f32x4 acc_o[4];
    #pragma unroll
    for (int n = 0; n < 4; n++) acc_o[n] = fzero;
    float m_run = -1e30f, l_run = 0.f;
    const float SCL2 = 0.125f * 1.4426950408889634f;  // scale * log2(e)

    // prologue stage kt=0 into buf 0
    {
        char* kl = (char*)&K_lds[0][0][0] + w * 2048;
        char* vl = (char*)&V_lds[0][0][0] + w * 2048;
        gload16(kg, kl); gload16(kg + kstep8, kl + 1024);
        gload16(vg, vl); gload16(vg + vstep8, vl + 1024);
    }

    for (int kt = 0; kt < NT; kt++) {
        const int buf = kt & 1;
        __syncthreads();   // drains vmcnt -> staged tile kt visible
        if (kt + 1 < NT) {
            char* kl = (char*)&K_lds[buf ^ 1][0][0] + w * 2048;
            char* vl = (char*)&V_lds[buf ^ 1][0][0] + w * 2048;
            const char* kp = kg + (size_t)(kt + 1) * kstep;
            const char* vp = vg + (size_t)(kt + 1) * 128;
            gload16(kp, kl); gload16(kp + kstep8, kl + 1024);
            gload16(vp, vl); gload16(vp + vstep8, vl + 1024);
        }

        // S^T = K Q^T : D[key][q], key = n*16 + 4g + r, q = lq
        const short* kb = &K_lds[buf][0][0];
        f32x4 st[4];
        #pragma unroll
        for (int n = 0; n < 4; n++) st[n] = fzero;
        #pragma unroll
        for (int kk = 0; kk < 2; kk++) {
            #pragma unroll
            for (int n = 0; n < 4; n++) {
                bf16x8 kf = ldfrag16(kb + (n * 16 + lq) * 64 + swzA[kk]);
                st[n] = __builtin_amdgcn_mfma_f32_16x16x32_bf16(kf, qf[kk], st[n], 0, 0, 0);
            }
        }

        // in-register online softmax (exp2 domain), stats per lane's q = lq
        float p[4][4];
        float mt = -1e30f;
        #pragma unroll
        for (int n = 0; n < 4; n++)
            #pragma unroll
            for (int r = 0; r < 4; r++) { p[n][r] = st[n][r] * SCL2; mt = fmaxf(mt, p[n][r]); }
        mt = fmaxf(mt, __shfl_xor(mt, 16));
        mt = fmaxf(mt, __shfl_xor(mt, 32));
        float mnew  = fmaxf(m_run, mt);
        float alpha = exp2f(m_run - mnew);
        float rs = 0.f;
        #pragma unroll
        for (int n = 0; n < 4; n++)
            #pragma unroll
            for (int r = 0; r < 4; r++) { p[n][r] = exp2f(p[n][r] - mnew); rs += p[n][r]; }
        rs += __shfl_xor(rs, 16);
        rs += __shfl_xor(rs, 32);
        l_run = l_run * alpha + rs;
        m_run = mnew;

        // rescale O (O-frag rows are q_local = 4g + r -> fetch alpha from lane 4g+r)
        float al[4];
        #pragma unroll
        for (int r = 0; r < 4; r++) al[r] = __shfl(alpha, (g << 2) + r);
        #pragma unroll
        for (int nd = 0; nd < 4; nd++)
            #pragma unroll
            for (int r = 0; r < 4; r++) acc_o[nd][r] *= al[r];

        // P -> per-wave swizzled LDS (bf16), then PV
        short* pw = &P_lds[w][0][0];
        #pragma unroll
        for (int n = 0; n < 4; n++) {
            unsigned int d0 = cvtpk(p[n][0], p[n][1]);
            unsigned int d1 = cvtpk(p[n][2], p[n][3]);
            *(uint2*)((char*)pw + pwoff[n]) = make_uint2(d0, d1);
        }

        const short* vb = &V_lds[buf][0][0];
        #pragma unroll
        for (int kk = 0; kk < 2; kk++) {
            bf16x8 pf = ldfrag16(pw + lq * 64 + swzA[kk]);
            #pragma unroll
            for (int nd = 0; nd < 4; nd++) {
                bf16x8 vf = ldfrag16(vb + (nd * 16 + lq) * 64 + swzA[kk]);
                acc_o[nd] = __builtin_amdgcn_mfma_f32_16x16x32_bf16(pf, vf, acc_o[nd], 0, 0, 0);
            }
        }
    }

    // epilogue: normalize and store fp32
    float rl[4];
    #pragma unroll
    for (int r = 0; r < 4; r++) rl[r] = 1.0f / __shfl(l_run, (g << 2) + r);
    #pragma unroll
    for (int nd = 0; nd < 4; nd++) {
        #pragma unroll
        for (int r = 0; r < 4; r++) {
            int row = qw + g * 4 + r;
            int col = h * HDK + nd * 16 + lq;
            out[(size_t)row * DIM + col] = acc_o[nd][r] * rl[r];
        }
    }
}

extern "C" void kernel_launch(void* const* d_in, const int* in_sizes, int n_in,
                              void* d_out, int out_size, void* d_ws, size_t ws_size,
                              hipStream_t stream) {
    const float* x  = (const float*)d_in[0];
    const float* Wq = (const float*)d_in[1];
    const float* bq = (const float*)d_in[2];
    const float* Wk = (const float*)d_in[3];
    const float* bk = (const float*)d_in[4];
    const float* Wv = (const float*)d_in[5];
    const float* bv = (const float*)d_in[6];
    float* out = (float*)d_out;

    unsigned short* Qb = (unsigned short*)d_ws;
    unsigned short* Kb = Qb + (size_t)SEQ * DIM;
    unsigned short* Vt = Kb + (size_t)SEQ * DIM;

    dim3 g1(DIM / 128, SEQ / 128, 3);
    proj_kernel<<<g1, 256, 0, stream>>>(x, Wq, bq, Wk, bk, Wv, bv, Qb, Kb, Vt);

    dim3 g2(SEQ / 64, NH);
    attn_kernel<<<g2, 256, 0, stream>>>(Qb, Kb, Vt, out);
}